// Round 1
// baseline (1135.033 us; speedup 1.0000x reference)
//
#include <hip/hip_runtime.h>

#define D_FEAT 128

// ---- mode 0 helpers (GCN symmetric normalization) ----

__global__ void deg_kernel(const int* __restrict__ src, float* __restrict__ deg,
                           int E, const int* __restrict__ mode) {
    if (*mode == 1) return;
    int e = blockIdx.x * blockDim.x + threadIdx.x;
    if (e < E) atomicAdd(&deg[src[e]], 1.0f);
}

__global__ void norm_kernel(const float* __restrict__ deg, float* __restrict__ norm,
                            int N, const int* __restrict__ mode) {
    if (*mode == 1) return;
    int i = blockIdx.x * blockDim.x + threadIdx.x;
    if (i < N) norm[i] = rsqrtf(deg[i]);  // deg==0 -> inf, matches powf(0,-0.5)
}

// ---- main scatter: 32 lanes per edge, one float4 per lane ----

__global__ void scatter_kernel(const float* __restrict__ h, const float* __restrict__ w,
                               const int* __restrict__ src, const int* __restrict__ dst,
                               const float* __restrict__ norm, float* __restrict__ out,
                               int E, const int* __restrict__ mode) {
    long long gid = (long long)blockIdx.x * blockDim.x + threadIdx.x;
    int e = (int)(gid >> 5);   // 32 threads per edge (128 feats / 4 per float4)
    int lane = (int)(gid & 31);
    if (e >= E) return;
    int s = src[e];
    int d = dst[e];
    float scale = (*mode == 1) ? w[e] : norm[s];
    const float4* hp = (const float4*)(h + (long long)s * D_FEAT);
    float4 v = hp[lane];
    float* op = out + (long long)d * D_FEAT + lane * 4;
    atomicAdd(op + 0, v.x * scale);
    atomicAdd(op + 1, v.y * scale);
    atomicAdd(op + 2, v.z * scale);
    atomicAdd(op + 3, v.w * scale);
}

// ---- mode 0 final scaling: out[n,:] *= norm[n] ----

__global__ void scale_kernel(float* __restrict__ out, const float* __restrict__ norm,
                             int N, const int* __restrict__ mode) {
    if (*mode == 1) return;
    int idx = blockIdx.x * blockDim.x + threadIdx.x;   // one float4 per thread
    int total = N * (D_FEAT / 4);
    if (idx >= total) return;
    int node = idx / (D_FEAT / 4);
    float4* op = (float4*)out + idx;
    float4 v = *op;
    float nn = norm[node];
    v.x *= nn; v.y *= nn; v.z *= nn; v.w *= nn;
    *op = v;
}

extern "C" void kernel_launch(void* const* d_in, const int* in_sizes, int n_in,
                              void* d_out, int out_size, void* d_ws, size_t ws_size,
                              hipStream_t stream) {
    const float* h   = (const float*)d_in[0];
    const float* w   = (const float*)d_in[1];
    const int*   src = (const int*)d_in[2];
    const int*   dst = (const int*)d_in[3];
    const int*   mode = (const int*)d_in[4];

    int ND = in_sizes[0];          // N * D
    int E  = in_sizes[1];          // w is [E,1]
    int N  = ND / D_FEAT;

    float* out  = (float*)d_out;
    float* deg  = (float*)d_ws;        // N floats
    float* norm = deg + N;             // N floats

    // Harness poisons d_out/d_ws to 0xAA every call — zero what we accumulate into.
    hipMemsetAsync(d_out, 0, (size_t)out_size * sizeof(float), stream);
    hipMemsetAsync(d_ws, 0, (size_t)N * sizeof(float), stream);

    deg_kernel<<<(E + 255) / 256, 256, 0, stream>>>(src, deg, E, mode);
    norm_kernel<<<(N + 255) / 256, 256, 0, stream>>>(deg, norm, N, mode);

    long long total_threads = (long long)E * 32;
    int blocks = (int)((total_threads + 255) / 256);
    scatter_kernel<<<blocks, 256, 0, stream>>>(h, w, src, dst, norm, out, E, mode);

    int scale_total = N * (D_FEAT / 4);
    scale_kernel<<<(scale_total + 255) / 256, 256, 0, stream>>>(out, norm, N, mode);
}

// Round 2
// 285.274 us; speedup vs baseline: 3.9787x; 3.9787x over previous
//
#include <hip/hip_runtime.h>

#define D_FEAT 128

// ================= CSR-bucketing path (no fp32 atomics) =================
//
// ws layout (all 4-byte words), N = nodes, E = edges:
//   cnt    [0,   N)     int    in-degree histogram (zeroed)
//   deg    [N,  2N)     float  out-degree (mode 0 only, zeroed)
//   off    [2N, 3N+1)   int    exclusive prefix of cnt
//   cursor [3N+1,4N+1)  int    bucket fill cursors (init = off)
//   norm   [4N+1,5N+1)  float  deg^-1/2 (mode 0)
//   ssrc   [5N+1, +E)   int    src ids bucketed by dst
//   sw     [.., +E)     float  per-edge scale bucketed by dst

__global__ void hist_kernel(const int* __restrict__ src, const int* __restrict__ dst,
                            int* __restrict__ cnt, float* __restrict__ deg,
                            int E, const int* __restrict__ mode) {
    int e = blockIdx.x * blockDim.x + threadIdx.x;
    if (e >= E) return;
    atomicAdd(&cnt[dst[e]], 1);
    if (*mode != 1) atomicAdd(&deg[src[e]], 1.0f);
}

// single block, 1024 threads: exclusive scan of cnt -> off (+cursor), norm for mode 0
__global__ void scan_kernel(const int* __restrict__ cnt, int* __restrict__ off,
                            int* __restrict__ cursor, const float* __restrict__ deg,
                            float* __restrict__ norm, int N, const int* __restrict__ mode) {
    __shared__ int sdata[1024];
    __shared__ int carry_s;
    int tid = threadIdx.x;
    if (tid == 0) carry_s = 0;
    __syncthreads();
    for (int base = 0; base < N; base += 1024) {
        int i = base + tid;
        int x = (i < N) ? cnt[i] : 0;
        sdata[tid] = x;
        __syncthreads();
        for (int ofs = 1; ofs < 1024; ofs <<= 1) {
            int v = (tid >= ofs) ? sdata[tid - ofs] : 0;
            __syncthreads();
            sdata[tid] += v;
            __syncthreads();
        }
        int incl = sdata[tid];
        int carry = carry_s;
        if (i < N) { int ex = carry + incl - x; off[i] = ex; cursor[i] = ex; }
        __syncthreads();
        if (tid == 1023) carry_s = carry + incl;
        __syncthreads();
    }
    if (tid == 0) off[N] = carry_s;
    if (*mode != 1) {
        for (int i = tid; i < N; i += 1024) norm[i] = rsqrtf(deg[i]);
    }
}

__global__ void bucket_kernel(const int* __restrict__ src, const int* __restrict__ dst,
                              const float* __restrict__ w, const float* __restrict__ norm,
                              int* __restrict__ cursor, int* __restrict__ ssrc,
                              float* __restrict__ sw, int E, const int* __restrict__ mode) {
    int e = blockIdx.x * blockDim.x + threadIdx.x;
    if (e >= E) return;
    int d = dst[e];
    int pos = atomicAdd(&cursor[d], 1);
    int s = src[e];
    ssrc[pos] = s;
    sw[pos] = (*mode == 1) ? w[e] : norm[s];
}

// 32 lanes per dst node; each lane owns one float4 column slice of D=128.
__global__ void gather_kernel(const float* __restrict__ h, const int* __restrict__ off,
                              const int* __restrict__ ssrc, const float* __restrict__ sw,
                              const float* __restrict__ norm, float* __restrict__ out,
                              int N, const int* __restrict__ mode) {
    long long gid = (long long)blockIdx.x * blockDim.x + threadIdx.x;
    int node = (int)(gid >> 5);
    int lane = (int)(gid & 31);
    if (node >= N) return;
    int beg = off[node], end = off[node + 1];
    float ax = 0.f, ay = 0.f, az = 0.f, aw = 0.f;
    for (int j = beg; j < end; ++j) {
        int s = ssrc[j];
        float sc = sw[j];
        float4 v = ((const float4*)(h + (long long)s * D_FEAT))[lane];
        ax += v.x * sc; ay += v.y * sc; az += v.z * sc; aw += v.w * sc;
    }
    float fin = (*mode == 1) ? 1.0f : norm[node];
    float4 r; r.x = ax * fin; r.y = ay * fin; r.z = az * fin; r.w = aw * fin;
    ((float4*)(out + (long long)node * D_FEAT))[lane] = r;
}

// ================= fallback: atomic scatter (round-1 kernel) =================

__global__ void fb_deg_kernel(const int* __restrict__ src, float* __restrict__ deg,
                              int E, const int* __restrict__ mode) {
    if (*mode == 1) return;
    int e = blockIdx.x * blockDim.x + threadIdx.x;
    if (e < E) atomicAdd(&deg[src[e]], 1.0f);
}
__global__ void fb_norm_kernel(const float* __restrict__ deg, float* __restrict__ norm,
                               int N, const int* __restrict__ mode) {
    if (*mode == 1) return;
    int i = blockIdx.x * blockDim.x + threadIdx.x;
    if (i < N) norm[i] = rsqrtf(deg[i]);
}
__global__ void fb_scatter_kernel(const float* __restrict__ h, const float* __restrict__ w,
                                  const int* __restrict__ src, const int* __restrict__ dst,
                                  const float* __restrict__ norm, float* __restrict__ out,
                                  int E, const int* __restrict__ mode) {
    long long gid = (long long)blockIdx.x * blockDim.x + threadIdx.x;
    int e = (int)(gid >> 5);
    int lane = (int)(gid & 31);
    if (e >= E) return;
    int s = src[e], d = dst[e];
    float scale = (*mode == 1) ? w[e] : norm[s];
    float4 v = ((const float4*)(h + (long long)s * D_FEAT))[lane];
    float* op = out + (long long)d * D_FEAT + lane * 4;
    atomicAdd(op + 0, v.x * scale);
    atomicAdd(op + 1, v.y * scale);
    atomicAdd(op + 2, v.z * scale);
    atomicAdd(op + 3, v.w * scale);
}
__global__ void fb_scale_kernel(float* __restrict__ out, const float* __restrict__ norm,
                                int N, const int* __restrict__ mode) {
    if (*mode == 1) return;
    int idx = blockIdx.x * blockDim.x + threadIdx.x;
    int total = N * (D_FEAT / 4);
    if (idx >= total) return;
    int node = idx / (D_FEAT / 4);
    float4* op = (float4*)out + idx;
    float4 v = *op;
    float nn = norm[node];
    v.x *= nn; v.y *= nn; v.z *= nn; v.w *= nn;
    *op = v;
}

extern "C" void kernel_launch(void* const* d_in, const int* in_sizes, int n_in,
                              void* d_out, int out_size, void* d_ws, size_t ws_size,
                              hipStream_t stream) {
    const float* h    = (const float*)d_in[0];
    const float* w    = (const float*)d_in[1];
    const int*   src  = (const int*)d_in[2];
    const int*   dst  = (const int*)d_in[3];
    const int*   mode = (const int*)d_in[4];

    int ND = in_sizes[0];
    int E  = in_sizes[1];
    int N  = ND / D_FEAT;

    float* out = (float*)d_out;

    size_t need = ((size_t)5 * N + 1 + 2 * (size_t)E) * 4;
    if (ws_size >= need) {
        int*   cnt    = (int*)d_ws;
        float* deg    = (float*)(cnt + N);
        int*   off    = (int*)(deg + N);
        int*   cursor = off + N + 1;
        float* norm   = (float*)(cursor + N);
        int*   ssrc   = (int*)(norm + N);
        float* sw     = (float*)(ssrc + E);

        // zero cnt + deg (adjacent, 2N words)
        hipMemsetAsync(d_ws, 0, (size_t)2 * N * sizeof(int), stream);

        hist_kernel<<<(E + 255) / 256, 256, 0, stream>>>(src, dst, cnt, deg, E, mode);
        scan_kernel<<<1, 1024, 0, stream>>>(cnt, off, cursor, deg, norm, N, mode);
        bucket_kernel<<<(E + 255) / 256, 256, 0, stream>>>(src, dst, w, norm, cursor,
                                                           ssrc, sw, E, mode);
        long long gt = (long long)N * 32;
        gather_kernel<<<(int)((gt + 255) / 256), 256, 0, stream>>>(h, off, ssrc, sw,
                                                                   norm, out, N, mode);
    } else {
        // fallback: atomic scatter
        float* deg  = (float*)d_ws;
        float* norm = deg + N;
        hipMemsetAsync(d_out, 0, (size_t)out_size * sizeof(float), stream);
        hipMemsetAsync(d_ws, 0, (size_t)N * sizeof(float), stream);
        fb_deg_kernel<<<(E + 255) / 256, 256, 0, stream>>>(src, deg, E, mode);
        fb_norm_kernel<<<(N + 255) / 256, 256, 0, stream>>>(deg, norm, N, mode);
        long long tt = (long long)E * 32;
        fb_scatter_kernel<<<(int)((tt + 255) / 256), 256, 0, stream>>>(h, w, src, dst,
                                                                       norm, out, E, mode);
        int st = N * (D_FEAT / 4);
        fb_scale_kernel<<<(st + 255) / 256, 256, 0, stream>>>(out, norm, N, mode);
    }
}

// Round 3
// 205.235 us; speedup vs baseline: 5.5304x; 1.3900x over previous
//
#include <hip/hip_runtime.h>

#define D_FEAT 128
#define SCAN_BS 1024

// ================= CSR-bucketing path (no fp32 atomics) =================
//
// ws layout (4-byte words), N = nodes, E = edges, nb = ceil(N/1024):
//   cnt    [0,   N)       int    in-degree histogram (zeroed)
//   deg    [N,  2N)       float  out-degree (mode 0 only, zeroed)
//   off    [2N, 3N+1)     int    exclusive prefix of cnt (off[N] = E)
//   cursor [3N+1,4N+1)    int    bucket fill cursors (init = off)
//   norm   [4N+1,5N+1)    float  deg^-1/2 (mode 0)
//   bsum   [5N+1, +nb)    int    per-block sums
//   boff   [.., +nb)      int    exclusive scan of bsum
//   ssrc   [.., +E)       int    src ids bucketed by dst
//   sw     [.., +E)       float  per-edge scale bucketed by dst

__global__ void hist_kernel(const int* __restrict__ src, const int* __restrict__ dst,
                            int* __restrict__ cnt, float* __restrict__ deg,
                            int E, const int* __restrict__ mode) {
    int e = blockIdx.x * blockDim.x + threadIdx.x;
    if (e >= E) return;
    atomicAdd(&cnt[dst[e]], 1);
    if (*mode != 1) atomicAdd(&deg[src[e]], 1.0f);
}

// Level 1: per-block exclusive scan of cnt -> off (block-local), block sums -> bsum
__global__ void block_scan_kernel(const int* __restrict__ cnt, int* __restrict__ off,
                                  int* __restrict__ bsum, int N) {
    __shared__ int sdata[SCAN_BS];
    int tid = threadIdx.x;
    int i = blockIdx.x * SCAN_BS + tid;
    int x = (i < N) ? cnt[i] : 0;
    sdata[tid] = x;
    __syncthreads();
    for (int ofs = 1; ofs < SCAN_BS; ofs <<= 1) {
        int v = (tid >= ofs) ? sdata[tid - ofs] : 0;
        __syncthreads();
        sdata[tid] += v;
        __syncthreads();
    }
    if (i < N) off[i] = sdata[tid] - x;          // block-local exclusive
    if (tid == SCAN_BS - 1) bsum[blockIdx.x] = sdata[tid];
}

// Level 2: scan the nb block sums (single wave if nb<=64, else serial loop)
__global__ void scan_sums_kernel(const int* __restrict__ bsum, int* __restrict__ boff,
                                 int* __restrict__ offN, int nb) {
    if (nb <= 64) {
        int lane = threadIdx.x;                  // launched with 64 threads
        int x = (lane < nb) ? bsum[lane] : 0;
        int incl = x;
        #pragma unroll
        for (int ofs = 1; ofs < 64; ofs <<= 1) {
            int v = __shfl_up(incl, ofs, 64);
            if (lane >= ofs) incl += v;
        }
        if (lane < nb) boff[lane] = incl - x;
        if (lane == 63) *offN = incl;
    } else if (threadIdx.x == 0) {
        int acc = 0;
        for (int b = 0; b < nb; ++b) { boff[b] = acc; acc += bsum[b]; }
        *offN = acc;
    }
}

// Level 3: add block offsets, init cursors, compute norm (mode 0)
__global__ void finalize_kernel(int* __restrict__ off, int* __restrict__ cursor,
                                const int* __restrict__ boff, const float* __restrict__ deg,
                                float* __restrict__ norm, int N, const int* __restrict__ mode) {
    int i = blockIdx.x * blockDim.x + threadIdx.x;
    if (i >= N) return;
    int v = off[i] + boff[i / SCAN_BS];
    off[i] = v;
    cursor[i] = v;
    if (*mode != 1) norm[i] = rsqrtf(deg[i]);    // deg==0 -> inf, matches powf(0,-0.5)
}

__global__ void bucket_kernel(const int* __restrict__ src, const int* __restrict__ dst,
                              const float* __restrict__ w, const float* __restrict__ norm,
                              int* __restrict__ cursor, int* __restrict__ ssrc,
                              float* __restrict__ sw, int E, const int* __restrict__ mode) {
    int e = blockIdx.x * blockDim.x + threadIdx.x;
    if (e >= E) return;
    int d = dst[e];
    int pos = atomicAdd(&cursor[d], 1);
    int s = src[e];
    ssrc[pos] = s;
    sw[pos] = (*mode == 1) ? w[e] : norm[s];
}

// 32 lanes per dst node; each lane owns one float4 column slice of D=128.
__global__ void gather_kernel(const float* __restrict__ h, const int* __restrict__ off,
                              const int* __restrict__ ssrc, const float* __restrict__ sw,
                              const float* __restrict__ norm, float* __restrict__ out,
                              int N, const int* __restrict__ mode) {
    long long gid = (long long)blockIdx.x * blockDim.x + threadIdx.x;
    int node = (int)(gid >> 5);
    int lane = (int)(gid & 31);
    if (node >= N) return;
    int beg = off[node], end = off[node + 1];
    float ax = 0.f, ay = 0.f, az = 0.f, aw = 0.f;
    for (int j = beg; j < end; ++j) {
        int s = ssrc[j];
        float sc = sw[j];
        float4 v = ((const float4*)(h + (long long)s * D_FEAT))[lane];
        ax += v.x * sc; ay += v.y * sc; az += v.z * sc; aw += v.w * sc;
    }
    float fin = (*mode == 1) ? 1.0f : norm[node];
    float4 r; r.x = ax * fin; r.y = ay * fin; r.z = az * fin; r.w = aw * fin;
    ((float4*)(out + (long long)node * D_FEAT))[lane] = r;
}

// ================= fallback: atomic scatter =================

__global__ void fb_deg_kernel(const int* __restrict__ src, float* __restrict__ deg,
                              int E, const int* __restrict__ mode) {
    if (*mode == 1) return;
    int e = blockIdx.x * blockDim.x + threadIdx.x;
    if (e < E) atomicAdd(&deg[src[e]], 1.0f);
}
__global__ void fb_norm_kernel(const float* __restrict__ deg, float* __restrict__ norm,
                               int N, const int* __restrict__ mode) {
    if (*mode == 1) return;
    int i = blockIdx.x * blockDim.x + threadIdx.x;
    if (i < N) norm[i] = rsqrtf(deg[i]);
}
__global__ void fb_scatter_kernel(const float* __restrict__ h, const float* __restrict__ w,
                                  const int* __restrict__ src, const int* __restrict__ dst,
                                  const float* __restrict__ norm, float* __restrict__ out,
                                  int E, const int* __restrict__ mode) {
    long long gid = (long long)blockIdx.x * blockDim.x + threadIdx.x;
    int e = (int)(gid >> 5);
    int lane = (int)(gid & 31);
    if (e >= E) return;
    int s = src[e], d = dst[e];
    float scale = (*mode == 1) ? w[e] : norm[s];
    float4 v = ((const float4*)(h + (long long)s * D_FEAT))[lane];
    float* op = out + (long long)d * D_FEAT + lane * 4;
    atomicAdd(op + 0, v.x * scale);
    atomicAdd(op + 1, v.y * scale);
    atomicAdd(op + 2, v.z * scale);
    atomicAdd(op + 3, v.w * scale);
}
__global__ void fb_scale_kernel(float* __restrict__ out, const float* __restrict__ norm,
                                int N, const int* __restrict__ mode) {
    if (*mode == 1) return;
    int idx = blockIdx.x * blockDim.x + threadIdx.x;
    int total = N * (D_FEAT / 4);
    if (idx >= total) return;
    int node = idx / (D_FEAT / 4);
    float4* op = (float4*)out + idx;
    float4 v = *op;
    float nn = norm[node];
    v.x *= nn; v.y *= nn; v.z *= nn; v.w *= nn;
    *op = v;
}

extern "C" void kernel_launch(void* const* d_in, const int* in_sizes, int n_in,
                              void* d_out, int out_size, void* d_ws, size_t ws_size,
                              hipStream_t stream) {
    const float* h    = (const float*)d_in[0];
    const float* w    = (const float*)d_in[1];
    const int*   src  = (const int*)d_in[2];
    const int*   dst  = (const int*)d_in[3];
    const int*   mode = (const int*)d_in[4];

    int ND = in_sizes[0];
    int E  = in_sizes[1];
    int N  = ND / D_FEAT;
    int nb = (N + SCAN_BS - 1) / SCAN_BS;

    float* out = (float*)d_out;

    size_t need = ((size_t)5 * N + 1 + 2 * (size_t)nb + 2 * (size_t)E) * 4;
    if (ws_size >= need) {
        int*   cnt    = (int*)d_ws;
        float* deg    = (float*)(cnt + N);
        int*   off    = (int*)(deg + N);
        int*   cursor = off + N + 1;
        float* norm   = (float*)(cursor + N);
        int*   bsum   = (int*)(norm + N);
        int*   boff   = bsum + nb;
        int*   ssrc   = boff + nb;
        float* sw     = (float*)(ssrc + E);

        // zero cnt + deg (adjacent, 2N words)
        hipMemsetAsync(d_ws, 0, (size_t)2 * N * sizeof(int), stream);

        hist_kernel<<<(E + 255) / 256, 256, 0, stream>>>(src, dst, cnt, deg, E, mode);
        block_scan_kernel<<<nb, SCAN_BS, 0, stream>>>(cnt, off, bsum, N);
        scan_sums_kernel<<<1, 64, 0, stream>>>(bsum, boff, &off[N], nb);
        finalize_kernel<<<(N + 255) / 256, 256, 0, stream>>>(off, cursor, boff, deg,
                                                             norm, N, mode);
        bucket_kernel<<<(E + 255) / 256, 256, 0, stream>>>(src, dst, w, norm, cursor,
                                                           ssrc, sw, E, mode);
        long long gt = (long long)N * 32;
        gather_kernel<<<(int)((gt + 255) / 256), 256, 0, stream>>>(h, off, ssrc, sw,
                                                                   norm, out, N, mode);
    } else {
        // fallback: atomic scatter
        float* deg  = (float*)d_ws;
        float* norm = deg + N;
        hipMemsetAsync(d_out, 0, (size_t)out_size * sizeof(float), stream);
        hipMemsetAsync(d_ws, 0, (size_t)N * sizeof(float), stream);
        fb_deg_kernel<<<(E + 255) / 256, 256, 0, stream>>>(src, deg, E, mode);
        fb_norm_kernel<<<(N + 255) / 256, 256, 0, stream>>>(deg, norm, N, mode);
        long long tt = (long long)E * 32;
        fb_scatter_kernel<<<(int)((tt + 255) / 256), 256, 0, stream>>>(h, w, src, dst,
                                                                       norm, out, E, mode);
        int st = N * (D_FEAT / 4);
        fb_scale_kernel<<<(st + 255) / 256, 256, 0, stream>>>(out, norm, N, mode);
    }
}